// Round 5
// baseline (258.638 us; speedup 1.0000x reference)
//
#include <hip/hip_runtime.h>

// Problem: y[b,l,o] = sum_{k,i} x[b, idx[l,k], i] * mask[k,i,o] + bias[o]
// B=4, L=10000, K=16, I=256, O=256  => gathered GEMM M=40000, N=256, KK=4096
#define Bdim 4
#define Ldim 10000
#define Kdim 16
#define Idim 256
#define Odim 256

typedef __attribute__((ext_vector_type(8))) __bf16 bf16x8;
typedef __attribute__((ext_vector_type(4))) float f32x4;

// ---------------- fused pre-pass ----------------
// blocks [0,2500): convert x fp32->bf16 (4096 floats per block: 256 thr x 16)
// blocks [2500,3012): pack mask into B-fragment order Wpk[c][lane][8],
//                     c = kb*32 + wid*8 + ks*4 + ni
__global__ __launch_bounds__(256)
void prepack(const float* __restrict__ x, const float* __restrict__ mask,
             __bf16* __restrict__ xb, __bf16* __restrict__ wpk)
{
    const int b = blockIdx.x;
    if (b < 2500) {
        const size_t base = ((size_t)b * 256 + threadIdx.x) * 16;
#pragma unroll
        for (int j = 0; j < 2; ++j) {
            const float4 f0 = *(const float4*)(x + base + j * 8);
            const float4 f1 = *(const float4*)(x + base + j * 8 + 4);
            bf16x8 v;
            v[0] = (__bf16)f0.x; v[1] = (__bf16)f0.y; v[2] = (__bf16)f0.z; v[3] = (__bf16)f0.w;
            v[4] = (__bf16)f1.x; v[5] = (__bf16)f1.y; v[6] = (__bf16)f1.z; v[7] = (__bf16)f1.w;
            *(bf16x8*)(xb + base + j * 8) = v;
        }
    } else {
        const int tg = (b - 2500) * 256 + threadIdx.x;    // 0..131071
        const int c  = tg >> 6;                            // chunk 0..2047
        const int ln = tg & 63;
        const int ni  = c & 3;
        const int ks  = (c >> 2) & 1;
        const int wid = (c >> 3) & 3;
        const int kb  = c >> 5;
        const int n   = wid * 64 + ni * 16 + (ln & 15);
        const int kk0 = kb * 64 + ks * 32 + (ln >> 4) * 8;
        bf16x8 v;
#pragma unroll
        for (int j = 0; j < 8; ++j)
            v[j] = (__bf16)mask[(size_t)(kk0 + j) * Odim + n];
        *(bf16x8*)(wpk + (size_t)tg * 8) = v;
    }
}

// ---------------- main GEMM: no-LDS register-gather version ----------------
// Grid (625, 2): block = 2 waves (128 thr). Wave w owns batches {2w, 2w+1}
// (M-split: each wave gathers its OWN A rows -> no LDS staging, no data
// barriers). Wave covers M=32 (2 mi-frags) x N=128 (8 ni-frags), acc[2][8].
// BK=32 (one 16x16x32 k-slice per step), 128 steps.
// Operand economics per MFMA: A 128B (reg-gather, ni=8 reuse across... A
// shared by 8 ni), W 512B/wave but the block's 2 waves read identical W
// (L1 reuse; loose pacing via a bare s_barrier every 2 steps).
#define TL 16          // l per block -> 625 x-blocks
#define IDXS 17        // idx_lds row stride (conflict-free)

__global__ __launch_bounds__(128, 3)
void piconv_gemm(const __bf16* __restrict__ xb,
                 const int* __restrict__ idxT,
                 const __bf16* __restrict__ wpk,
                 const float* __restrict__ bias,
                 float* __restrict__ out)
{
    __shared__ int idx_lds[TL * IDXS];     // 16 l x 16 k, stride 17

    const int t    = threadIdx.x;          // 0..127
    const int l0   = blockIdx.x * TL;
    const int nh   = blockIdx.y;           // N-half: cols [nh*128, nh*128+128)
    const int lane = t & 63;
    const int w    = t >> 6;               // wave 0/1 -> batches {2w, 2w+1}
    const int q    = lane >> 4;
    const int r16  = lane & 15;
    const int qo   = q * 8;                // k-offset within 32-slice

    // stage idx table (256 entries)
#pragma unroll
    for (int it = 0; it < 2; ++it) {
        const int e = t + it * 128;
        idx_lds[(e >> 4) * IDXS + (e & 15)] = idxT[l0 * Kdim + e];
    }

    // per-wave A row bases (batch 2w+mi), element offsets
    const size_t abase0 = (size_t)(w * 2 + 0) * Ldim * Idim;
    const size_t abase1 = (size_t)(w * 2 + 1) * Ldim * Idim;
    // W base for this N-half (wid = nh*2 + (j>>2))
    const __bf16* wb = wpk + (size_t)nh * 8192 + lane * 8;

    f32x4  acc[2][8] = {};
    bf16x8 aE[2], aO[2];                   // A slots for even/odd steps (2-deep)
    bf16x8 wA[8], wB[8];                   // W double buffer (1-step ahead)

    __syncthreads();                       // idx table ready (only full sync)

    // prologue: A(0)->aE, A(1)->aO (kn=0 for both), W(0)->wA (kb=0,ks=0)
    {
        const int iv = idx_lds[r16 * IDXS];
        const __bf16* s = xb + abase0 + (((size_t)iv) << 8) + qo;
        aE[0] = *(const bf16x8*)(s);
        aO[0] = *(const bf16x8*)(s + 32);
        const __bf16* s1 = xb + abase1 + (((size_t)iv) << 8) + qo;
        aE[1] = *(const bf16x8*)(s1);
        aO[1] = *(const bf16x8*)(s1 + 32);
#pragma unroll
        for (int j = 0; j < 4; ++j) {
            wA[j]     = *(const bf16x8*)(wb + j * 512);
            wA[j + 4] = *(const bf16x8*)(wb + 4096 + j * 512);
        }
    }

// step S: MFMA with ACUR/WCUR; prefetch W(S+1)->WNXT, A(S+2)->ACUR.
#define STEPZ(S, ACUR, WCUR, WNXT, PFA, PFW)                                    \
    {                                                                           \
        int iv_pf = 0;                                                          \
        if (PFA) iv_pf = idx_lds[r16 * IDXS + (((S) + 2) >> 3)];                \
        if (PFW) {                                                              \
            const __bf16* wq = wb + (size_t)(((S) + 1) >> 1) * 16384            \
                                  + (((S) + 1) & 1) * 2048;                     \
            _Pragma("unroll")                                                   \
            for (int j = 0; j < 4; ++j) {                                       \
                WNXT[j]     = *(const bf16x8*)(wq + j * 512);                   \
                WNXT[j + 4] = *(const bf16x8*)(wq + 4096 + j * 512);            \
            }                                                                   \
        }                                                                       \
        _Pragma("unroll")                                                       \
        for (int mi = 0; mi < 2; ++mi)                                          \
            _Pragma("unroll")                                                   \
            for (int ni = 0; ni < 8; ++ni)                                      \
                acc[mi][ni] = __builtin_amdgcn_mfma_f32_16x16x32_bf16(          \
                    ACUR[mi], WCUR[ni], acc[mi][ni], 0, 0, 0);                  \
        if (PFA) {                                                              \
            const int io = (((S) + 2) & 7) * 32 + qo;                           \
            ACUR[0] = *(const bf16x8*)(xb + abase0 + (((size_t)iv_pf) << 8) + io); \
            ACUR[1] = *(const bf16x8*)(xb + abase1 + (((size_t)iv_pf) << 8) + io); \
        }                                                                       \
    }

    // steps 0..125 in 63 unrolled pairs; bare barrier (no waitcnt drain)
    // every 2 steps keeps the 2 waves loosely paced for W L1-reuse.
    for (int s2 = 0; s2 < 63; ++s2) {
        const int S = 2 * s2;
        STEPZ(S,     aE, wA, wB, true, true)
        STEPZ(S + 1, aO, wB, wA, true, true)
        __builtin_amdgcn_s_barrier();
    }
    // tail: S=126 (no A prefetch), S=127 (no prefetch at all)
    STEPZ(126, aE, wA, wB, false, true)
    STEPZ(127, aO, wB, wA, false, false)
#undef STEPZ

    // ---- epilogue: C/D layout col=lane&15, row=(lane>>4)*4+reg ----
    float bv[8];
#pragma unroll
    for (int ni = 0; ni < 8; ++ni)
        bv[ni] = bias[nh * 128 + ni * 16 + r16];
#pragma unroll
    for (int mi = 0; mi < 2; ++mi) {
#pragma unroll
        for (int rr = 0; rr < 4; ++rr) {
            const int lt = q * 4 + rr;     // l-offset 0..15
            float* dst = out + (((size_t)((w * 2 + mi) * Ldim + l0 + lt)) << 8)
                             + nh * 128 + r16;
#pragma unroll
            for (int ni = 0; ni < 8; ++ni)
                dst[ni * 16] = acc[mi][ni][rr] + bv[ni];
        }
    }
}

// ---------------- fallback (no-ws path) ----------------
#define FTL 32
#define FBN 128
#define FLDA 72
__global__ __launch_bounds__(256)
void piconv_fallback(const float* __restrict__ x,
                     const int* __restrict__ idxT,
                     const float* __restrict__ mask,
                     const float* __restrict__ bias,
                     float* __restrict__ out)
{
    __shared__ __bf16 Alds[128 * FLDA];
    __shared__ __bf16 Wlds[FBN * FLDA];
    const int t  = threadIdx.x;
    const int l0 = blockIdx.x * FTL;
    const int n0 = blockIdx.y * FBN;
    const int lane = t & 63;
    const int wid  = t >> 6;
    const int wm   = wid >> 1;
    const int wn   = wid & 1;
    const int q    = lane >> 4;
    const int r16  = lane & 15;
    f32x4 acc[4][4] = {};
    const int am    = t >> 1;
    const int ahalf = t & 1;
    const int alt   = am & 31;
    const int abb   = am >> 5;
    const int al    = l0 + alt;
    const bool avalid = (al < Ldim);
    for (int kb = 0; kb < 64; ++kb) {
        {
            const int ksl = kb >> 2;
            const int i0  = ((kb & 3) << 6) + (ahalf << 5);
            const int idx = avalid ? idxT[al * Kdim + ksl] : 0;
            const float* src = x + (((size_t)(abb * Ldim + idx)) << 8) + i0;
#pragma unroll
            for (int j = 0; j < 4; ++j) {
                const float4 f0 = *(const float4*)(src + j * 8);
                const float4 f1 = *(const float4*)(src + j * 8 + 4);
                bf16x8 v;
                v[0] = (__bf16)f0.x; v[1] = (__bf16)f0.y; v[2] = (__bf16)f0.z; v[3] = (__bf16)f0.w;
                v[4] = (__bf16)f1.x; v[5] = (__bf16)f1.y; v[6] = (__bf16)f1.z; v[7] = (__bf16)f1.w;
                *(bf16x8*)&Alds[am * FLDA + (ahalf << 5) + j * 8] = v;
            }
        }
        {
#pragma unroll
            for (int it = 0; it < 4; ++it) {
                const int pair = t + it * 256;
                const int n    = pair & 127;
                const int g    = pair >> 7;
                const float* src = mask + (((size_t)(kb * 64 + g * 8)) << 8) + n0 + n;
                bf16x8 v;
#pragma unroll
                for (int j = 0; j < 8; ++j)
                    v[j] = (__bf16)src[(size_t)j << 8];
                *(bf16x8*)&Wlds[n * FLDA + g * 8] = v;
            }
        }
        __syncthreads();
#pragma unroll
        for (int ks = 0; ks < 2; ++ks) {
            bf16x8 af[4], bfr[4];
#pragma unroll
            for (int mi = 0; mi < 4; ++mi)
                af[mi] = *(bf16x8*)&Alds[(wm * 64 + mi * 16 + r16) * FLDA + ks * 32 + q * 8];
#pragma unroll
            for (int ni = 0; ni < 4; ++ni)
                bfr[ni] = *(bf16x8*)&Wlds[(wn * 64 + ni * 16 + r16) * FLDA + ks * 32 + q * 8];
#pragma unroll
            for (int mi = 0; mi < 4; ++mi)
#pragma unroll
                for (int ni = 0; ni < 4; ++ni)
                    acc[mi][ni] = __builtin_amdgcn_mfma_f32_16x16x32_bf16(
                        af[mi], bfr[ni], acc[mi][ni], 0, 0, 0);
        }
        __syncthreads();
    }
    float bv[4];
#pragma unroll
    for (int ni = 0; ni < 4; ++ni)
        bv[ni] = bias[n0 + wn * 64 + ni * 16 + r16];
#pragma unroll
    for (int mi = 0; mi < 4; ++mi) {
        const int mrow = wm * 64 + mi * 16 + q * 4;
#pragma unroll
        for (int rr = 0; rr < 4; ++rr) {
            const int m  = mrow + rr;
            const int lt = m & 31;
            const int bb = m >> 5;
            const int l  = l0 + lt;
            if (l < Ldim) {
                float* dst = out + (((size_t)(bb * Ldim + l)) << 8) + n0 + wn * 64 + r16;
#pragma unroll
                for (int ni = 0; ni < 4; ++ni)
                    dst[ni * 16] = acc[mi][ni][rr] + bv[ni];
            }
        }
    }
}

extern "C" void kernel_launch(void* const* d_in, const int* in_sizes, int n_in,
                              void* d_out, int out_size, void* d_ws, size_t ws_size,
                              hipStream_t stream) {
    const float* x    = (const float*)d_in[0];
    const int*   idx  = (const int*)d_in[1];
    const float* mask = (const float*)d_in[2];
    const float* bias = (const float*)d_in[3];
    float* out = (float*)d_out;

    const size_t xb_bytes = (size_t)Bdim * Ldim * Idim * 2;   // 20,480,000
    const size_t wp_bytes = (size_t)Kdim * Idim * Odim * 2;   //  2,097,152

    if (ws_size >= xb_bytes + wp_bytes) {
        __bf16* xb  = (__bf16*)d_ws;
        __bf16* wpk = (__bf16*)((char*)d_ws + xb_bytes);
        // 2500 x-convert blocks (2500*256*16 = 10,240,000 floats, exact) + 512 pack blocks
        prepack<<<2500 + 512, 256, 0, stream>>>(x, mask, xb, wpk);
        dim3 ggrid(Ldim / TL, 2, 1);
        piconv_gemm<<<ggrid, 128, 0, stream>>>(xb, idx, wpk, bias, out);
    } else {
        dim3 grid((Ldim + FTL - 1) / FTL, Odim / FBN, 1);
        piconv_fallback<<<grid, 256, 0, stream>>>(x, idx, mask, bias, out);
    }
}

// Round 6
// 185.215 us; speedup vs baseline: 1.3964x; 1.3964x over previous
//
#include <hip/hip_runtime.h>

// Problem: y[b,l,o] = sum_{k,i} x[b, idx[l,k], i] * mask[k,i,o] + bias[o]
// B=4, L=10000, K=16, I=256, O=256  => gathered GEMM M=40000, N=256, KK=4096
#define Bdim 4
#define Ldim 10000
#define Kdim 16
#define Idim 256
#define Odim 256

typedef __attribute__((ext_vector_type(8))) __bf16 bf16x8;
typedef __attribute__((ext_vector_type(4))) float f32x4;

// ---------------- fused pre-pass ----------------
// blocks [0,2500): convert x fp32->bf16 (4096 floats per block: 256 thr x 16)
// blocks [2500,3012): pack mask into B-fragment order Wpk[c][lane][8],
//                     c = kb*32 + wid*8 + ks*4 + ni
__global__ __launch_bounds__(256)
void prepack(const float* __restrict__ x, const float* __restrict__ mask,
             __bf16* __restrict__ xb, __bf16* __restrict__ wpk)
{
    const int b = blockIdx.x;
    if (b < 2500) {
        const size_t base = ((size_t)b * 256 + threadIdx.x) * 16;
#pragma unroll
        for (int j = 0; j < 2; ++j) {
            const float4 f0 = *(const float4*)(x + base + j * 8);
            const float4 f1 = *(const float4*)(x + base + j * 8 + 4);
            bf16x8 v;
            v[0] = (__bf16)f0.x; v[1] = (__bf16)f0.y; v[2] = (__bf16)f0.z; v[3] = (__bf16)f0.w;
            v[4] = (__bf16)f1.x; v[5] = (__bf16)f1.y; v[6] = (__bf16)f1.z; v[7] = (__bf16)f1.w;
            *(bf16x8*)(xb + base + j * 8) = v;
        }
    } else {
        const int tg = (b - 2500) * 256 + threadIdx.x;    // 0..131071
        const int c  = tg >> 6;                            // chunk 0..2047
        const int ln = tg & 63;
        const int ni  = c & 3;
        const int ks  = (c >> 2) & 1;
        const int wid = (c >> 3) & 3;
        const int kb  = c >> 5;
        const int n   = wid * 64 + ni * 16 + (ln & 15);
        const int kk0 = kb * 64 + ks * 32 + (ln >> 4) * 8;
        bf16x8 v;
#pragma unroll
        for (int j = 0; j < 8; ++j)
            v[j] = (__bf16)mask[(size_t)(kk0 + j) * Odim + n];
        *(bf16x8*)(wpk + (size_t)tg * 8) = v;
    }
}

// ---------------- main GEMM: R2 skeleton + ring-4 A-LDS ----------------
// Ring pipeline (per step S): compute from slot S%4; ds_write A(S+2) into
// slot (S+2)%4 (data gathered at S-2); issue gather A(S+4). Barrier only at
// even steps. Write->read gap = 2 steps (was 0), gather issue->consume =
// 4 steps (was 2), barriers halved. Race-free: >=1 lgkmcnt(0)+barrier
// separates every LDS write from its readers and every read from the
// slot's next rewrite (both parities checked).
#define TL 16          // l per block -> 625 blocks exact
#define BM 64          // = Bdim * TL
#define LDA 72         // LDS row stride in bf16 (64 + 8 pad)

// Barrier WITHOUT the vmcnt(0) drain __syncthreads would emit.
#define BARRIER() do { asm volatile("s_waitcnt lgkmcnt(0)" ::: "memory"); \
                       __builtin_amdgcn_s_barrier(); } while (0)

__global__ __launch_bounds__(256, 3)
void piconv_gemm(const __bf16* __restrict__ xb,
                 const int* __restrict__ idxT,
                 const __bf16* __restrict__ wpk,
                 const float* __restrict__ bias,
                 float* __restrict__ out)
{
    __shared__ __bf16 Alds[4][BM * LDA];   // 4 x 9.2 KB ring
    __shared__ int    idx_lds[TL * Kdim];  // 1 KB

    const int t    = threadIdx.x;
    const int l0   = blockIdx.x * TL;
    const int lane = t & 63;
    const int wid  = t >> 6;               // n-quadrant: n in [wid*64, wid*64+64)
    const int q    = lane >> 4;
    const int r16  = lane & 15;

    idx_lds[t] = idxT[l0 * Kdim + t];      // 256 = TL*Kdim

    // A staging: 4 threads per row, 16 bf16 (32 B) each
    const int arow  = t >> 2;              // 0..63
    const int apart = t & 3;
    const int alt   = arow & 15;
    const int abb   = arow >> 4;
    const size_t abase = ((size_t)abb * Ldim) << 8;

    // W fragment base: + kb*16384 + (ks*4+ni)*512; 1024 B contiguous per wave-load
    const __bf16* wbase = wpk + ((size_t)(wid * 8) << 9) + lane * 8;

    f32x4  acc[4][4] = {};
    bf16x8 aE0, aE1;                       // A regs, even-step data
    bf16x8 aO0, aO1;                       // A regs, odd-step data
    bf16x8 wA[8], wB[8];

    __syncthreads();                       // idx table ready

    // prologue: A(0)->slot0, A(1)->slot1 (direct), W(0)->wA,
    //           A(2)->aE, A(3)->aO  (kn=0 for steps 0..3)
    {
        const int iv = idx_lds[alt * Kdim];
        const __bf16* s = xb + abase + (((size_t)iv) << 8) + apart * 16;
        const bf16x8 t0 = *(const bf16x8*)(s);
        const bf16x8 t1 = *(const bf16x8*)(s + 8);
        const bf16x8 t2 = *(const bf16x8*)(s + 64);
        const bf16x8 t3 = *(const bf16x8*)(s + 72);
        *(bf16x8*)&Alds[0][arow * LDA + apart * 16]     = t0;
        *(bf16x8*)&Alds[0][arow * LDA + apart * 16 + 8] = t1;
        *(bf16x8*)&Alds[1][arow * LDA + apart * 16]     = t2;
        *(bf16x8*)&Alds[1][arow * LDA + apart * 16 + 8] = t3;
#pragma unroll
        for (int j = 0; j < 8; ++j)
            wA[j] = *(const bf16x8*)(wbase + j * 512);
        aE0 = *(const bf16x8*)(s + 128);
        aE1 = *(const bf16x8*)(s + 136);
        aO0 = *(const bf16x8*)(s + 192);
        aO1 = *(const bf16x8*)(s + 200);
    }
    __syncthreads();                       // slots 0,1 visible

// step S = SB + J (J compile-time 0..3, SB multiple of 4).
// WRF: ds_write A(S+2) -> slot (J+2)&3   (valid S<=61)
// PAF: issue gather A(S+4) -> AR regs    (valid S<=59)
// PWF: load W(S+1) -> WNXT               (valid S<=62)
#define STEP(J, SB, WCUR, WNXT, AR0, AR1, WRF, PAF, PWF)                        \
    {                                                                           \
        if (((J) & 1) == 0) BARRIER();                                          \
        if (PWF) {                                                              \
            const __bf16* wq = wbase + ((size_t)((SB) + (J) + 1)) * 16384;      \
            _Pragma("unroll")                                                   \
            for (int j = 0; j < 8; ++j)                                         \
                WNXT[j] = *(const bf16x8*)(wq + j * 512);                       \
        }                                                                       \
        if (WRF) {                                                              \
            *(bf16x8*)&Alds[((J) + 2) & 3][arow * LDA + apart * 16]     = AR0;  \
            *(bf16x8*)&Alds[((J) + 2) & 3][arow * LDA + apart * 16 + 8] = AR1;  \
        }                                                                       \
        if (PAF) {                                                              \
            const int T  = (SB) + (J) + 4;                                      \
            const int iv = idx_lds[alt * Kdim + (T >> 2)];                      \
            const __bf16* s = xb + abase + (((size_t)iv) << 8)                  \
                              + (((J) & 3) << 6) + apart * 16;                  \
            AR0 = *(const bf16x8*)(s);                                          \
            AR1 = *(const bf16x8*)(s + 8);                                      \
        }                                                                       \
        _Pragma("unroll")                                                       \
        for (int ks = 0; ks < 2; ++ks) {                                        \
            bf16x8 af[4];                                                       \
            _Pragma("unroll")                                                   \
            for (int mi = 0; mi < 4; ++mi)                                      \
                af[mi] = *(bf16x8*)&Alds[(J) & 3][(mi * 16 + r16) * LDA + ks * 32 + q * 8]; \
            _Pragma("unroll")                                                   \
            for (int mi = 0; mi < 4; ++mi)                                      \
                _Pragma("unroll")                                               \
                for (int ni = 0; ni < 4; ++ni)                                  \
                    acc[mi][ni] = __builtin_amdgcn_mfma_f32_16x16x32_bf16(      \
                        af[mi], WCUR[ks * 4 + ni], acc[mi][ni], 0, 0, 0);       \
        }                                                                       \
    }

    // steady state: steps 0..59 (15 iterations x 4 steps, all flags true)
    for (int s4 = 0; s4 < 15; ++s4) {
        const int SB = s4 * 4;
        STEP(0, SB, wA, wB, aE0, aE1, true, true, true)
        STEP(1, SB, wB, wA, aO0, aO1, true, true, true)
        STEP(2, SB, wA, wB, aE0, aE1, true, true, true)
        STEP(3, SB, wB, wA, aO0, aO1, true, true, true)
    }
    // tail: steps 60..63
    STEP(0, 60, wA, wB, aE0, aE1, true,  false, true)
    STEP(1, 60, wB, wA, aO0, aO1, true,  false, true)
    STEP(2, 60, wA, wB, aE0, aE1, false, false, true)
    STEP(3, 60, wB, wA, aO0, aO1, false, false, false)
#undef STEP

    // ---- epilogue: C/D layout col=lane&15, row=(lane>>4)*4+reg ----
    float bv[4];
#pragma unroll
    for (int ni = 0; ni < 4; ++ni)
        bv[ni] = bias[wid * 64 + ni * 16 + r16];
#pragma unroll
    for (int mi = 0; mi < 4; ++mi) {          // mi = batch index (BM=64 = 4b x 16l)
#pragma unroll
        for (int rr = 0; rr < 4; ++rr) {
            const int lt = q * 4 + rr;
            float* dst = out + (((size_t)(mi * Ldim + l0 + lt)) << 8) + wid * 64 + r16;
#pragma unroll
            for (int ni = 0; ni < 4; ++ni)
                dst[ni * 16] = acc[mi][ni][rr] + bv[ni];
        }
    }
}

// ---------------- fallback (no-ws path) ----------------
#define FTL 32
#define FBN 128
#define FLDA 72
__global__ __launch_bounds__(256)
void piconv_fallback(const float* __restrict__ x,
                     const int* __restrict__ idxT,
                     const float* __restrict__ mask,
                     const float* __restrict__ bias,
                     float* __restrict__ out)
{
    __shared__ __bf16 Alds[128 * FLDA];
    __shared__ __bf16 Wlds[FBN * FLDA];
    const int t  = threadIdx.x;
    const int l0 = blockIdx.x * FTL;
    const int n0 = blockIdx.y * FBN;
    const int lane = t & 63;
    const int wid  = t >> 6;
    const int wm   = wid >> 1;
    const int wn   = wid & 1;
    const int q    = lane >> 4;
    const int r16  = lane & 15;
    f32x4 acc[4][4] = {};
    const int am    = t >> 1;
    const int ahalf = t & 1;
    const int alt   = am & 31;
    const int abb   = am >> 5;
    const int al    = l0 + alt;
    const bool avalid = (al < Ldim);
    for (int kb = 0; kb < 64; ++kb) {
        {
            const int ksl = kb >> 2;
            const int i0  = ((kb & 3) << 6) + (ahalf << 5);
            const int idx = avalid ? idxT[al * Kdim + ksl] : 0;
            const float* src = x + (((size_t)(abb * Ldim + idx)) << 8) + i0;
#pragma unroll
            for (int j = 0; j < 4; ++j) {
                const float4 f0 = *(const float4*)(src + j * 8);
                const float4 f1 = *(const float4*)(src + j * 8 + 4);
                bf16x8 v;
                v[0] = (__bf16)f0.x; v[1] = (__bf16)f0.y; v[2] = (__bf16)f0.z; v[3] = (__bf16)f0.w;
                v[4] = (__bf16)f1.x; v[5] = (__bf16)f1.y; v[6] = (__bf16)f1.z; v[7] = (__bf16)f1.w;
                *(bf16x8*)&Alds[am * FLDA + (ahalf << 5) + j * 8] = v;
            }
        }
        {
#pragma unroll
            for (int it = 0; it < 4; ++it) {
                const int pair = t + it * 256;
                const int n    = pair & 127;
                const int g    = pair >> 7;
                const float* src = mask + (((size_t)(kb * 64 + g * 8)) << 8) + n0 + n;
                bf16x8 v;
#pragma unroll
                for (int j = 0; j < 8; ++j)
                    v[j] = (__bf16)src[(size_t)j << 8];
                *(bf16x8*)&Wlds[n * FLDA + g * 8] = v;
            }
        }
        __syncthreads();
#pragma unroll
        for (int ks = 0; ks < 2; ++ks) {
            bf16x8 af[4], bfr[4];
#pragma unroll
            for (int mi = 0; mi < 4; ++mi)
                af[mi] = *(bf16x8*)&Alds[(wm * 64 + mi * 16 + r16) * FLDA + ks * 32 + q * 8];
#pragma unroll
            for (int ni = 0; ni < 4; ++ni)
                bfr[ni] = *(bf16x8*)&Wlds[(wn * 64 + ni * 16 + r16) * FLDA + ks * 32 + q * 8];
#pragma unroll
            for (int mi = 0; mi < 4; ++mi)
#pragma unroll
                for (int ni = 0; ni < 4; ++ni)
                    acc[mi][ni] = __builtin_amdgcn_mfma_f32_16x16x32_bf16(
                        af[mi], bfr[ni], acc[mi][ni], 0, 0, 0);
        }
        __syncthreads();
    }
    float bv[4];
#pragma unroll
    for (int ni = 0; ni < 4; ++ni)
        bv[ni] = bias[n0 + wn * 64 + ni * 16 + r16];
#pragma unroll
    for (int mi = 0; mi < 4; ++mi) {
        const int mrow = wm * 64 + mi * 16 + q * 4;
#pragma unroll
        for (int rr = 0; rr < 4; ++rr) {
            const int m  = mrow + rr;
            const int lt = m & 31;
            const int bb = m >> 5;
            const int l  = l0 + lt;
            if (l < Ldim) {
                float* dst = out + (((size_t)(bb * Ldim + l)) << 8) + n0 + wn * 64 + r16;
#pragma unroll
                for (int ni = 0; ni < 4; ++ni)
                    dst[ni * 16] = acc[mi][ni][rr] + bv[ni];
            }
        }
    }
}

extern "C" void kernel_launch(void* const* d_in, const int* in_sizes, int n_in,
                              void* d_out, int out_size, void* d_ws, size_t ws_size,
                              hipStream_t stream) {
    const float* x    = (const float*)d_in[0];
    const int*   idx  = (const int*)d_in[1];
    const float* mask = (const float*)d_in[2];
    const float* bias = (const float*)d_in[3];
    float* out = (float*)d_out;

    const size_t xb_bytes = (size_t)Bdim * Ldim * Idim * 2;   // 20,480,000
    const size_t wp_bytes = (size_t)Kdim * Idim * Odim * 2;   //  2,097,152

    if (ws_size >= xb_bytes + wp_bytes) {
        __bf16* xb  = (__bf16*)d_ws;
        __bf16* wpk = (__bf16*)((char*)d_ws + xb_bytes);
        // 2500 x-convert blocks (2500*256*16 = 10,240,000 floats, exact) + 512 pack blocks
        prepack<<<2500 + 512, 256, 0, stream>>>(x, mask, xb, wpk);
        piconv_gemm<<<Ldim / TL, 256, 0, stream>>>(xb, idx, wpk, bias, out);
    } else {
        dim3 grid((Ldim + FTL - 1) / FTL, Odim / FBN, 1);
        piconv_fallback<<<grid, 256, 0, stream>>>(x, idx, mask, bias, out);
    }
}

// Round 8
// 178.844 us; speedup vs baseline: 1.4462x; 1.0356x over previous
//
#include <hip/hip_runtime.h>

// Problem: y[b,l,o] = sum_{k,i} x[b, idx[l,k], i] * mask[k,i,o] + bias[o]
// B=4, L=10000, K=16, I=256, O=256  => gathered GEMM M=40000, N=256, KK=4096
#define Bdim 4
#define Ldim 10000
#define Kdim 16
#define Idim 256
#define Odim 256

typedef __attribute__((ext_vector_type(8))) __bf16 bf16x8;
typedef __attribute__((ext_vector_type(4))) float f32x4;

// ---------------- fused pre-pass ----------------
// blocks [0,2500): convert x fp32->bf16 (4096 floats per block: 256 thr x 16)
// blocks [2500,3012): pack mask into B-fragment order Wpk[c][lane][8],
//                     c = kb*32 + wid*8 + ks*4 + ni
__global__ __launch_bounds__(256)
void prepack(const float* __restrict__ x, const float* __restrict__ mask,
             __bf16* __restrict__ xb, __bf16* __restrict__ wpk)
{
    const int b = blockIdx.x;
    if (b < 2500) {
        const size_t base = ((size_t)b * 256 + threadIdx.x) * 16;
#pragma unroll
        for (int j = 0; j < 2; ++j) {
            const float4 f0 = *(const float4*)(x + base + j * 8);
            const float4 f1 = *(const float4*)(x + base + j * 8 + 4);
            bf16x8 v;
            v[0] = (__bf16)f0.x; v[1] = (__bf16)f0.y; v[2] = (__bf16)f0.z; v[3] = (__bf16)f0.w;
            v[4] = (__bf16)f1.x; v[5] = (__bf16)f1.y; v[6] = (__bf16)f1.z; v[7] = (__bf16)f1.w;
            *(bf16x8*)(xb + base + j * 8) = v;
        }
    } else {
        const int tg = (b - 2500) * 256 + threadIdx.x;    // 0..131071
        const int c  = tg >> 6;                            // chunk 0..2047
        const int ln = tg & 63;
        const int ni  = c & 3;
        const int ks  = (c >> 2) & 1;
        const int wid = (c >> 3) & 3;
        const int kb  = c >> 5;
        const int n   = wid * 64 + ni * 16 + (ln & 15);
        const int kk0 = kb * 64 + ks * 32 + (ln >> 4) * 8;
        bf16x8 v;
#pragma unroll
        for (int j = 0; j < 8; ++j)
            v[j] = (__bf16)mask[(size_t)(kk0 + j) * Odim + n];
        *(bf16x8*)(wpk + (size_t)tg * 8) = v;
    }
}

// ---------------- main GEMM: TL=20 + fragment-major LDS ----------------
// Grid 500 blocks (244 CUs x2, 12 x1 -> critical path 2 blocks vs 3 at 625).
// BM = 80 rows = 4 batches x 20 l; wave mi=5, ni=4 (acc[5][4]).
// A staged in LDS in EXACT MFMA-fragment order: block (mi*2+ks) holds 512
// contiguous bf16 x8 fragments, compute ds_read = contiguous 1KB/wave
// (minimal bank cycles, zero conflict). Staging: 640 16B units/step,
// units A,B for all 256 threads + unit C on even threads (bijective).
// Schedule identical to R2: write -> lgkmcnt(0)+barrier -> prefetch
// A(S+1),W(S+1) -> 2ks x 5mi x 4ni MFMA.
// R7 BUG FIX: A prefetch here is ONE step ahead (A(S+1)), so step 62 MUST
// prefetch A(63) (R7 had PFA=false there, copied from R2's 2-ahead tail ->
// k-block 63 computed with k-block 62's A data, absmax 19).
#define TL 20          // l per block -> 500 blocks exact
#define BM 80          // = Bdim * TL
#define IDXS 17        // idx_lds k-stride (bank spread)

#define BARRIER() do { asm volatile("s_waitcnt lgkmcnt(0)" ::: "memory"); \
                       __builtin_amdgcn_s_barrier(); } while (0)

__global__ __launch_bounds__(256, 2)
void piconv_gemm(const __bf16* __restrict__ xb,
                 const int* __restrict__ idxT,
                 const __bf16* __restrict__ wpk,
                 const float* __restrict__ bias,
                 float* __restrict__ out)
{
    __shared__ __bf16 Alds[2][BM * 64];    // 2 x 10.0 KB, fragment-major
    __shared__ int    idx_lds[TL * IDXS];  // 20 l x 16 k, stride 17

    const int t    = threadIdx.x;
    const int l0   = blockIdx.x * TL;
    const int lane = t & 63;
    const int wid  = t >> 6;               // n-quadrant: n in [wid*64, wid*64+64)
    const int q    = lane >> 4;
    const int r16  = lane & 15;

    // stage idx table: 320 entries -> [l][k] at stride 17
    {
        const int e0 = t;
        idx_lds[(e0 >> 4) * IDXS + (e0 & 15)] = idxT[l0 * Kdim + e0];
        if (t < 64) {
            const int e1 = t + 256;
            idx_lds[(e1 >> 4) * IDXS + (e1 & 15)] = idxT[l0 * Kdim + e1];
        }
    }

    // ---- staging unit constants (3 units per thread, C masked to even t) ----
    // unit A: rows 0..31,  unit B: rows 32..63, unit C: rows 64..79 (even t)
    const int rA = t & 31,               pA = t >> 5;       // part 0..7
    const int rB = 32 + (t & 31);
    const int rC = 64 + ((t >> 1) & 15);
    const bool cAct = (t & 1) == 0;
    // row r = abb*TL + alt  (abb = batch, alt = l-offset)
    const int abbA = rA / TL, altA = rA % TL;
    const int abbB = rB / TL, altB = rB % TL;
    const int abbC = rC / TL, altC = rC % TL;
    const size_t abaseA = ((size_t)abbA * Ldim) << 8;
    const size_t abaseB = ((size_t)abbB * Ldim) << 8;
    const size_t abaseC = ((size_t)abbC * Ldim) << 8;
    // fragment-major LDS element offset: ((r>>4)*2 + (p>>2))*512 + (p&3)*128 + (r&15)*8
    const int dsA = (((rA >> 4) * 2 + (pA >> 2)) * 512) + ((pA & 3) * 128) + ((rA & 15) * 8);
    const int dsB = (((rB >> 4) * 2 + (pA >> 2)) * 512) + ((pA & 3) * 128) + ((rB & 15) * 8);
    const int dsC = (((rC >> 4) * 2 + (pA >> 2)) * 512) + ((pA & 3) * 128) + ((rC & 15) * 8);
    const int po  = pA * 8;                // element offset of part within 64-k slice

    // W fragment base: + kb*16384 + (ks*4+ni)*512
    const __bf16* wbase = wpk + ((size_t)(wid * 8) << 9) + lane * 8;

    f32x4  acc[5][4] = {};
    bf16x8 aRA, aRB, aRC;
    bf16x8 wA[8], wB[8];

    __syncthreads();                       // idx table ready

    // prologue: gather A(0) -> regs, W(0) -> wA
    {
        const int ivA = idx_lds[altA * IDXS];
        const int ivB = idx_lds[altB * IDXS];
        aRA = *(const bf16x8*)(xb + abaseA + (((size_t)ivA) << 8) + po);
        aRB = *(const bf16x8*)(xb + abaseB + (((size_t)ivB) << 8) + po);
        if (cAct) {
            const int ivC = idx_lds[altC * IDXS];
            aRC = *(const bf16x8*)(xb + abaseC + (((size_t)ivC) << 8) + po);
        }
#pragma unroll
        for (int j = 0; j < 8; ++j)
            wA[j] = *(const bf16x8*)(wbase + j * 512);
    }

#define STEP(S, WCUR, WNXT, PFA, PFW)                                           \
    {                                                                           \
        __bf16* db = &Alds[(S) & 1][0];                                         \
        *(bf16x8*)(db + dsA) = aRA;                                             \
        *(bf16x8*)(db + dsB) = aRB;                                             \
        if (cAct) *(bf16x8*)(db + dsC) = aRC;                                   \
        BARRIER();                                                              \
        if (PFA) {  /* gather A(S+1) */                                         \
            const int T   = (S) + 1;                                            \
            const int kn  = T >> 2;                                             \
            const int iob = ((T & 3) << 6) + po;                                \
            const int ivA = idx_lds[altA * IDXS + kn];                          \
            const int ivB = idx_lds[altB * IDXS + kn];                          \
            aRA = *(const bf16x8*)(xb + abaseA + (((size_t)ivA) << 8) + iob);   \
            aRB = *(const bf16x8*)(xb + abaseB + (((size_t)ivB) << 8) + iob);   \
            if (cAct) {                                                         \
                const int ivC = idx_lds[altC * IDXS + kn];                      \
                aRC = *(const bf16x8*)(xb + abaseC + (((size_t)ivC) << 8) + iob); \
            }                                                                   \
        }                                                                       \
        if (PFW) {  /* W(S+1) */                                                \
            const __bf16* wq = wbase + ((size_t)((S) + 1)) * 16384;             \
            _Pragma("unroll")                                                   \
            for (int j = 0; j < 8; ++j)                                         \
                WNXT[j] = *(const bf16x8*)(wq + j * 512);                       \
        }                                                                       \
        _Pragma("unroll")                                                       \
        for (int ks = 0; ks < 2; ++ks) {                                        \
            bf16x8 af[5];                                                       \
            _Pragma("unroll")                                                   \
            for (int mi = 0; mi < 5; ++mi)                                      \
                af[mi] = *(const bf16x8*)(&Alds[(S) & 1][(mi * 2 + ks) * 512 + lane * 8]); \
            _Pragma("unroll")                                                   \
            for (int mi = 0; mi < 5; ++mi)                                      \
                _Pragma("unroll")                                               \
                for (int ni = 0; ni < 4; ++ni)                                  \
                    acc[mi][ni] = __builtin_amdgcn_mfma_f32_16x16x32_bf16(      \
                        af[mi], WCUR[ks * 4 + ni], acc[mi][ni], 0, 0, 0);       \
        }                                                                       \
    }

    for (int s2 = 0; s2 < 31; ++s2) {
        STEP(2 * s2,     wA, wB, true, true)
        STEP(2 * s2 + 1, wB, wA, true, true)
    }
    // tail: step 62 still prefetches A(63) (1-ahead pipeline!); step 63 none
    STEP(62, wA, wB, true,  true)
    STEP(63, wB, wA, false, false)
#undef STEP

    // ---- epilogue: C/D layout col=lane&15, row=(lane>>4)*4+reg ----
    float bv[4];
#pragma unroll
    for (int ni = 0; ni < 4; ++ni)
        bv[ni] = bias[wid * 64 + ni * 16 + r16];
#pragma unroll
    for (int mi = 0; mi < 5; ++mi) {
#pragma unroll
        for (int rr = 0; rr < 4; ++rr) {
            const int r  = mi * 16 + q * 4 + rr;   // 0..79
            const int ab = r / TL;
            const int al = r % TL;
            float* dst = out + (((size_t)(ab * Ldim + l0 + al)) << 8) + wid * 64 + r16;
#pragma unroll
            for (int ni = 0; ni < 4; ++ni)
                dst[ni * 16] = acc[mi][ni][rr] + bv[ni];
        }
    }
}

// ---------------- fallback (no-ws path) ----------------
#define FTL 32
#define FBN 128
#define FLDA 72
__global__ __launch_bounds__(256)
void piconv_fallback(const float* __restrict__ x,
                     const int* __restrict__ idxT,
                     const float* __restrict__ mask,
                     const float* __restrict__ bias,
                     float* __restrict__ out)
{
    __shared__ __bf16 Alds[128 * FLDA];
    __shared__ __bf16 Wlds[FBN * FLDA];
    const int t  = threadIdx.x;
    const int l0 = blockIdx.x * FTL;
    const int n0 = blockIdx.y * FBN;
    const int lane = t & 63;
    const int wid  = t >> 6;
    const int wm   = wid >> 1;
    const int wn   = wid & 1;
    const int q    = lane >> 4;
    const int r16  = lane & 15;
    f32x4 acc[4][4] = {};
    const int am    = t >> 1;
    const int ahalf = t & 1;
    const int alt   = am & 31;
    const int abb   = am >> 5;
    const int al    = l0 + alt;
    const bool avalid = (al < Ldim);
    for (int kb = 0; kb < 64; ++kb) {
        {
            const int ksl = kb >> 2;
            const int i0  = ((kb & 3) << 6) + (ahalf << 5);
            const int idx = avalid ? idxT[al * Kdim + ksl] : 0;
            const float* src = x + (((size_t)(abb * Ldim + idx)) << 8) + i0;
#pragma unroll
            for (int j = 0; j < 4; ++j) {
                const float4 f0 = *(const float4*)(src + j * 8);
                const float4 f1 = *(const float4*)(src + j * 8 + 4);
                bf16x8 v;
                v[0] = (__bf16)f0.x; v[1] = (__bf16)f0.y; v[2] = (__bf16)f0.z; v[3] = (__bf16)f0.w;
                v[4] = (__bf16)f1.x; v[5] = (__bf16)f1.y; v[6] = (__bf16)f1.z; v[7] = (__bf16)f1.w;
                *(bf16x8*)&Alds[am * FLDA + (ahalf << 5) + j * 8] = v;
            }
        }
        {
#pragma unroll
            for (int it = 0; it < 4; ++it) {
                const int pair = t + it * 256;
                const int n    = pair & 127;
                const int g    = pair >> 7;
                const float* src = mask + (((size_t)(kb * 64 + g * 8)) << 8) + n0 + n;
                bf16x8 v;
#pragma unroll
                for (int j = 0; j < 8; ++j)
                    v[j] = (__bf16)src[(size_t)j << 8];
                *(bf16x8*)&Wlds[n * FLDA + g * 8] = v;
            }
        }
        __syncthreads();
#pragma unroll
        for (int ks = 0; ks < 2; ++ks) {
            bf16x8 af[4], bfr[4];
#pragma unroll
            for (int mi = 0; mi < 4; ++mi)
                af[mi] = *(bf16x8*)&Alds[(wm * 64 + mi * 16 + r16) * FLDA + ks * 32 + q * 8];
#pragma unroll
            for (int ni = 0; ni < 4; ++ni)
                bfr[ni] = *(bf16x8*)&Wlds[(wn * 64 + ni * 16 + r16) * FLDA + ks * 32 + q * 8];
#pragma unroll
            for (int mi = 0; mi < 4; ++mi)
#pragma unroll
                for (int ni = 0; ni < 4; ++ni)
                    acc[mi][ni] = __builtin_amdgcn_mfma_f32_16x16x32_bf16(
                        af[mi], bfr[ni], acc[mi][ni], 0, 0, 0);
        }
        __syncthreads();
    }
    float bv[4];
#pragma unroll
    for (int ni = 0; ni < 4; ++ni)
        bv[ni] = bias[n0 + wn * 64 + ni * 16 + r16];
#pragma unroll
    for (int mi = 0; mi < 4; ++mi) {
        const int mrow = wm * 64 + mi * 16 + q * 4;
#pragma unroll
        for (int rr = 0; rr < 4; ++rr) {
            const int m  = mrow + rr;
            const int lt = m & 31;
            const int bb = m >> 5;
            const int l  = l0 + lt;
            if (l < Ldim) {
                float* dst = out + (((size_t)(bb * Ldim + l)) << 8) + n0 + wn * 64 + r16;
#pragma unroll
                for (int ni = 0; ni < 4; ++ni)
                    dst[ni * 16] = acc[mi][ni][rr] + bv[ni];
            }
        }
    }
}

extern "C" void kernel_launch(void* const* d_in, const int* in_sizes, int n_in,
                              void* d_out, int out_size, void* d_ws, size_t ws_size,
                              hipStream_t stream) {
    const float* x    = (const float*)d_in[0];
    const int*   idx  = (const int*)d_in[1];
    const float* mask = (const float*)d_in[2];
    const float* bias = (const float*)d_in[3];
    float* out = (float*)d_out;

    const size_t xb_bytes = (size_t)Bdim * Ldim * Idim * 2;   // 20,480,000
    const size_t wp_bytes = (size_t)Kdim * Idim * Odim * 2;   //  2,097,152

    if (ws_size >= xb_bytes + wp_bytes) {
        __bf16* xb  = (__bf16*)d_ws;
        __bf16* wpk = (__bf16*)((char*)d_ws + xb_bytes);
        // 2500 x-convert blocks (2500*256*16 = 10,240,000 floats, exact) + 512 pack blocks
        prepack<<<2500 + 512, 256, 0, stream>>>(x, mask, xb, wpk);
        piconv_gemm<<<Ldim / TL, 256, 0, stream>>>(xb, idx, wpk, bias, out);
    } else {
        dim3 grid((Ldim + FTL - 1) / FTL, Odim / FBN, 1);
        piconv_fallback<<<grid, 256, 0, stream>>>(x, idx, mask, bias, out);
    }
}